// Round 1
// baseline (450.553 us; speedup 1.0000x reference)
//
#include <hip/hip_runtime.h>
#include <hip/hip_bf16.h>

// Problem constants: B=8, H=256, W=256, C=8, K=16
// S = B*H*W = 524288 source pixels; KC = 128; OUTC = 136
#define S_TOTAL   524288u
#define OUT_MAIN  67108864u   // S_TOTAL * 128
#define X_TOTAL   4194304u    // S_TOTAL * 8
#define NEG4LOG2PI (-7.3515082656373808f)

// ---------------- prep: invert lower-triangular L_k, compute base_k ----------------
__global__ void prep_kernel(const float* __restrict__ scale, float* __restrict__ minv,
                            float* __restrict__ base) {
    int k = threadIdx.x;
    if (k >= 16) return;
    float L[8][8];
    const float* Ls = scale + k * 64;
    for (int i = 0; i < 8; i++)
        for (int j = 0; j < 8; j++) L[i][j] = Ls[i * 8 + j];
    float M[8][8];
    for (int i = 0; i < 8; i++)
        for (int j = 0; j < 8; j++) M[i][j] = 0.f;
    // column-wise forward substitution: L * M[:,j] = e_j  (lower triangle only)
    for (int j = 0; j < 8; j++) {
        M[j][j] = 1.0f / L[j][j];
        for (int i = j + 1; i < 8; i++) {
            float s = 0.f;
            for (int m = j; m < i; m++) s += L[i][m] * M[m][j];
            M[i][j] = -s / L[i][i];
        }
    }
    float logdet = 0.f;
    for (int i = 0; i < 8; i++) logdet += logf(fabsf(L[i][i]));
    for (int i = 0; i < 8; i++)
        for (int j = 0; j < 8; j++) minv[k * 64 + i * 8 + j] = M[i][j];
    base[k] = -logdet + NEG4LOG2PI;
}

// ---------------- gauss: per source pixel, 16 gaussian densities ----------------
__global__ __launch_bounds__(256) void gauss_kernel(const float* __restrict__ x,
                                                    const float* __restrict__ minv,
                                                    const float* __restrict__ base,
                                                    const float* __restrict__ mean,
                                                    float* __restrict__ gauss) {
    __shared__ float sM[1024];   // 16 x 8x8 inverse matrices
    __shared__ float sMu[128];   // 16 x 8 means
    __shared__ float sB[16];     // 16 bases
    for (int t = threadIdx.x; t < 1024; t += 256) sM[t] = minv[t];
    if (threadIdx.x < 128) sMu[threadIdx.x] = mean[threadIdx.x];
    if (threadIdx.x < 16) sB[threadIdx.x] = base[threadIdx.x];
    __syncthreads();

    unsigned s = blockIdx.x * 256u + threadIdx.x;
    float4 a = ((const float4*)x)[s * 2u];
    float4 b = ((const float4*)x)[s * 2u + 1u];
    float xv[8] = {a.x, a.y, a.z, a.w, b.x, b.y, b.z, b.w};

    #pragma unroll
    for (int k = 0; k < 16; k++) {
        const float* M  = &sM[k * 64];
        const float* mu = &sMu[k * 8];
        float d[8];
        #pragma unroll
        for (int j = 0; j < 8; j++) d[j] = xv[j] - mu[j];
        float quad = 0.f;
        #pragma unroll
        for (int i = 0; i < 8; i++) {
            float y = 0.f;
            #pragma unroll
            for (int j = 0; j <= i; j++) y = fmaf(M[i * 8 + j], d[j], y);
            quad = fmaf(y, y, quad);
        }
        gauss[k * S_TOTAL + s] = __expf(fmaf(-0.5f, quad, sB[k]));
    }
}

// ---------------- out_main: gather-multiply-scatter, 4 elems/thread ----------------
// out flat (per pixel q, out-channel j): i = q*128+j ; kc = i>>19 ; rem = i & (2^19-1)
// value = gauss[(kc>>3)*S + rem] * x[rem*8 + (kc&7)]
__global__ __launch_bounds__(256) void out_main_kernel(const float* __restrict__ x,
                                                       const float* __restrict__ gauss,
                                                       float* __restrict__ out) {
    unsigned i = (blockIdx.x * 256u + threadIdx.x) * 4u;  // aligned to 4
    unsigned kc  = i >> 19;          // constant across the 4 (and across the block)
    unsigned k   = kc >> 3;
    unsigned c   = kc & 7u;
    unsigned rem = i & (S_TOTAL - 1u);
    float4 g = *(const float4*)&gauss[k * S_TOTAL + rem];
    float4 v;
    v.x = g.x * x[(rem + 0u) * 8u + c];
    v.y = g.y * x[(rem + 1u) * 8u + c];
    v.z = g.z * x[(rem + 2u) * 8u + c];
    v.w = g.w * x[(rem + 3u) * 8u + c];
    unsigned q = i >> 7;
    unsigned j = i & 127u;           // multiple of 4, run never crossed
    *(float4*)&out[q * 136u + 8u + j] = v;
}

// ---------------- copy_x: first 8 channels = x itself ----------------
__global__ __launch_bounds__(256) void copy_x_kernel(const float* __restrict__ x,
                                                     float* __restrict__ out) {
    unsigned o = (blockIdx.x * 256u + threadIdx.x) * 4u;
    unsigned q = o >> 3, c2 = o & 7u;     // c2 in {0,4}
    float4 v = *(const float4*)&x[o];
    *(float4*)&out[q * 136u + c2] = v;
}

// ---------------- fallback: fused recompute (if workspace too small) ----------------
__global__ __launch_bounds__(256) void fused_kernel(const float* __restrict__ x,
                                                    const float* __restrict__ scale,
                                                    const float* __restrict__ mean,
                                                    float* __restrict__ out) {
    __shared__ float sM[64];
    __shared__ float sMu[8];
    __shared__ float sB;
    unsigned i0 = blockIdx.x * 256u;
    unsigned kc = i0 >> 19;   // uniform within block (256 < 2^19, aligned)
    unsigned k = kc >> 3, c = kc & 7u;
    if (threadIdx.x == 0) {
        float L[8][8];
        const float* Ls = scale + k * 64;
        for (int i = 0; i < 8; i++)
            for (int j = 0; j < 8; j++) L[i][j] = Ls[i * 8 + j];
        float M[8][8];
        for (int i = 0; i < 8; i++)
            for (int j = 0; j < 8; j++) M[i][j] = 0.f;
        for (int j = 0; j < 8; j++) {
            M[j][j] = 1.0f / L[j][j];
            for (int i = j + 1; i < 8; i++) {
                float s = 0.f;
                for (int m = j; m < i; m++) s += L[i][m] * M[m][j];
                M[i][j] = -s / L[i][i];
            }
        }
        float logdet = 0.f;
        for (int i = 0; i < 8; i++) logdet += logf(fabsf(L[i][i]));
        for (int i = 0; i < 8; i++)
            for (int j = 0; j < 8; j++) sM[i * 8 + j] = M[i][j];
        for (int j = 0; j < 8; j++) sMu[j] = mean[k * 8 + j];
        sB = -logdet + NEG4LOG2PI;
    }
    __syncthreads();
    unsigned i = i0 + threadIdx.x;
    unsigned rem = i & (S_TOTAL - 1u);
    float4 a = ((const float4*)x)[rem * 2u];
    float4 b = ((const float4*)x)[rem * 2u + 1u];
    float xv[8] = {a.x, a.y, a.z, a.w, b.x, b.y, b.z, b.w};
    float d[8];
    #pragma unroll
    for (int j = 0; j < 8; j++) d[j] = xv[j] - sMu[j];
    float quad = 0.f;
    #pragma unroll
    for (int ii = 0; ii < 8; ii++) {
        float y = 0.f;
        #pragma unroll
        for (int j = 0; j <= ii; j++) y = fmaf(sM[ii * 8 + j], d[j], y);
        quad = fmaf(y, y, quad);
    }
    float g = __expf(fmaf(-0.5f, quad, sB));
    out[(i >> 7) * 136u + 8u + (i & 127u)] = g * xv[c];
}

extern "C" void kernel_launch(void* const* d_in, const int* in_sizes, int n_in,
                              void* d_out, int out_size, void* d_ws, size_t ws_size,
                              hipStream_t stream) {
    const float* x     = (const float*)d_in[0];
    const float* scale = (const float*)d_in[1];
    const float* mean  = (const float*)d_in[2];
    float* out = (float*)d_out;

    const size_t GAUSS_BYTES = (size_t)16 * S_TOTAL * 4;           // 33,554,432
    const size_t NEED = GAUSS_BYTES + 1024 * 4 + 16 * 4;

    if (ws_size >= NEED) {
        float* gauss = (float*)d_ws;
        float* minv  = (float*)((char*)d_ws + GAUSS_BYTES);
        float* base  = minv + 1024;
        prep_kernel<<<1, 64, 0, stream>>>(scale, minv, base);
        gauss_kernel<<<S_TOTAL / 256, 256, 0, stream>>>(x, minv, base, mean, gauss);
        out_main_kernel<<<OUT_MAIN / 4 / 256, 256, 0, stream>>>(x, gauss, out);
    } else {
        fused_kernel<<<OUT_MAIN / 256, 256, 0, stream>>>(x, scale, mean, out);
    }
    copy_x_kernel<<<X_TOTAL / 4 / 256, 256, 0, stream>>>(x, out);
}